// Round 1
// baseline (1986.570 us; speedup 1.0000x reference)
//
#include <hip/hip_runtime.h>

typedef short bf16x8 __attribute__((ext_vector_type(8)));
typedef float f32x4 __attribute__((ext_vector_type(4)));

#define BN_EPS 1e-5f

__device__ __forceinline__ unsigned short f2b(float x) {
    union { float f; unsigned u; } v; v.f = x;
    unsigned r = v.u + 0x7FFFu + ((v.u >> 16) & 1u);
    return (unsigned short)(r >> 16);
}

__device__ __forceinline__ void atomAddF(float* p, float v) {
    unsafeAtomicAdd(p, v);  // native global_atomic_add_f32 on gfx950
}

// ---------------- W transpose + cast: W[k][ci][co] (f32) -> WT[k][co][ciPad] (bf16) ----
__global__ void transpose_cast_w(const float* __restrict__ W, unsigned short* __restrict__ WT,
                                 int Cin, int Cout, int CinPad) {
    __shared__ float t[32][33];
    int co0 = blockIdx.x * 32, ci0 = blockIdx.y * 32, k = blockIdx.z;
    const float* Wk = W + (size_t)k * Cin * Cout;
    unsigned short* WTk = WT + (size_t)k * Cout * CinPad;
    int tc = threadIdx.x & 31, tr = threadIdx.x >> 5;
    for (int i = 0; i < 4; i++) {
        int r = tr + i * 8;
        int ci = ci0 + r;
        t[r][tc] = (ci < Cin) ? Wk[(size_t)ci * Cout + co0 + tc] : 0.f;
    }
    __syncthreads();
    for (int i = 0; i < 4; i++) {
        int r = tr + i * 8;
        WTk[(size_t)(co0 + r) * CinPad + ci0 + tc] = f2b(t[tc][r]);
    }
}

// ---------------- cast fp32 [N,Csrc] -> bf16 at dst[n*stride + off + j], zero-fill j>=Csrc
__global__ void cast_cols(const float* __restrict__ src, unsigned short* __restrict__ dst,
                          int N, int Csrc, int stride, int off, int wid) {
    int i = blockIdx.x * blockDim.x + threadIdx.x;
    if (i >= N * wid) return;
    int n = i / wid, j = i % wid;
    float v = (j < Csrc) ? src[(size_t)n * Csrc + j] : 0.f;
    dst[(size_t)n * stride + off + j] = f2b(v);
}

// ---------------- BN stats: per-channel sum & sumsq over rows ----------------
__global__ void bn_stats(const float* __restrict__ x, float* __restrict__ stats,
                         int N, int C, int rowsPerBlock) {
    int r0 = blockIdx.x * rowsPerBlock;
    int r1 = min(N, r0 + rowsPerBlock);
    for (int c = threadIdx.x; c < C; c += blockDim.x) {
        float s = 0.f, s2 = 0.f;
        for (int r = r0; r < r1; r++) {
            float v = x[(size_t)r * C + c];
            s += v; s2 += v * v;
        }
        atomAddF(&stats[c], s);
        atomAddF(&stats[C + c], s2);
    }
}

// ---------------- BN apply + ReLU -> bf16 (strided dst, for concat) ----------
__global__ void bn_apply_bf16(const float* __restrict__ x, const float* __restrict__ stats,
                              const float* __restrict__ g, const float* __restrict__ b,
                              unsigned short* __restrict__ dst, int N, int C, int stride, float invN) {
    int i = blockIdx.x * blockDim.x + threadIdx.x;
    if (i >= N * C) return;
    int n = i / C, c = i % C;
    float mean = stats[c] * invN;
    float var = stats[C + c] * invN - mean * mean;
    float scale = g[c] * rsqrtf(var + BN_EPS);
    float shift = b[c] - mean * scale;
    float y = fmaxf(0.f, x[i] * scale + shift);
    dst[(size_t)n * stride + c] = f2b(y);
}

// ---------------- BN apply + ReLU in-place fp32 (final output) ---------------
__global__ void bn_apply_f32(float* __restrict__ x, const float* __restrict__ stats,
                             const float* __restrict__ g, const float* __restrict__ b,
                             int N, int C, float invN) {
    int i = blockIdx.x * blockDim.x + threadIdx.x;
    if (i >= N * C) return;
    int c = i % C;
    float mean = stats[c] * invN;
    float var = stats[C + c] * invN - mean * mean;
    float scale = g[c] * rsqrtf(var + BN_EPS);
    float shift = b[c] - mean * scale;
    x[i] = fmaxf(0.f, x[i] * scale + shift);
}

// ---------------- gather-GEMM-scatter conv (one k-offset per blockIdx.z) -----
// A: bf16 [Nin, Cin] (Cin = padded row stride), BT: bf16 [K][Cout][Cin]
// out: fp32 [Nout, Cout]; scatter-add via out_idx (or direct store if DENSE)
template<int TM, int TN, bool DENSE>
__global__ __launch_bounds__(256)
void conv_mfma(const unsigned short* __restrict__ A, const unsigned short* __restrict__ BT,
               const int* __restrict__ in_idx, const int* __restrict__ out_idx,
               float* __restrict__ out, int M, int Cin, int Cout) {
    constexpr int WM = TM / 32;   // 16-row frags per wave (2x2 wave grid)
    constexpr int WN = TN / 32;
    __shared__ unsigned short As[TM][40];   // 40-short rows: 16B-aligned, 2-way-free banks
    __shared__ unsigned short Bs[TN][40];

    int tid = threadIdx.x;
    int wave = tid >> 6, lane = tid & 63;
    int wr = wave >> 1, wc = wave & 1;
    int m0 = blockIdx.x * TM;
    int n0 = blockIdx.y * TN;
    int kz = blockIdx.z;

    int sr = tid >> 2, sseg = tid & 3;   // staging: 4 threads x 16B per 32-elem row
    int am = m0 + sr;
    bool avalid = (am < M);
    int arow;
    if constexpr (DENSE) arow = avalid ? am : 0;
    else                 arow = avalid ? in_idx[(size_t)kz * M + am] : 0;
    const unsigned short* Arowp = A + (size_t)arow * Cin + sseg * 8;
    bool bvalid = (sr < TN);
    const unsigned short* Browp = BT + (size_t)kz * Cout * Cin
                                     + (size_t)(n0 + (bvalid ? sr : 0)) * Cin + sseg * 8;

    f32x4 acc[WM][WN];
    for (int i = 0; i < WM; i++)
        for (int j = 0; j < WN; j++)
            acc[i][j] = (f32x4)(0.f);

    int laneM = lane & 15, laneK = (lane >> 4) * 8;

    for (int kc = 0; kc < Cin; kc += 32) {
        __syncthreads();
        uint4 av = {0, 0, 0, 0};
        if (avalid) av = *(const uint4*)(Arowp + kc);
        *(uint4*)&As[sr][sseg * 8] = av;
        if (bvalid) {
            uint4 bv = *(const uint4*)(Browp + kc);
            *(uint4*)&Bs[sr][sseg * 8] = bv;
        }
        __syncthreads();
        bf16x8 af[WM], bfr[WN];
        for (int i = 0; i < WM; i++)
            af[i] = *(const bf16x8*)&As[wr * (TM / 2) + i * 16 + laneM][laneK];
        for (int j = 0; j < WN; j++)
            bfr[j] = *(const bf16x8*)&Bs[wc * (TN / 2) + j * 16 + laneM][laneK];
        for (int i = 0; i < WM; i++)
            for (int j = 0; j < WN; j++)
                acc[i][j] = __builtin_amdgcn_mfma_f32_16x16x32_bf16(af[i], bfr[j], acc[i][j], 0, 0, 0);
    }

    // epilogue: C/D layout col=lane&15, row=(lane>>4)*4+reg  [m89/m91 verified]
    int rbase = (lane >> 4) * 4;
    for (int i = 0; i < WM; i++) {
        for (int j = 0; j < WN; j++) {
            int col = n0 + wc * (TN / 2) + j * 16 + laneM;
            for (int r = 0; r < 4; r++) {
                int gm = m0 + wr * (TM / 2) + i * 16 + rbase + r;
                if (gm < M) {
                    float v = acc[i][j][r];
                    if constexpr (DENSE) {
                        out[(size_t)gm * Cout + col] = v;
                    } else {
                        int orow = out_idx[(size_t)kz * M + gm];
                        atomAddF(&out[(size_t)orow * Cout + col], v);
                    }
                }
            }
        }
    }
}

static inline int div_up(int a, int b) { return (a + b - 1) / b; }

extern "C" void kernel_launch(void* const* d_in, const int* in_sizes, int n_in,
                              void* d_out, int out_size, void* d_ws, size_t ws_size,
                              hipStream_t stream) {
    const float* f0 = (const float*)d_in[0];
    const float* f1 = (const float*)d_in[1];
    const float* f2 = (const float*)d_in[2];
    const float* f3 = (const float*)d_in[3];
    const float* W_up2 = (const float*)d_in[4];
    const float* W_up1 = (const float*)d_in[5];
    const float* W_up0 = (const float*)d_in[6];
    const float* W_s0  = (const float*)d_in[7];
    const float* W_s1  = (const float*)d_in[8];
    const float* W_s2  = (const float*)d_in[9];
    const float* g_up2 = (const float*)d_in[10]; const float* b_up2 = (const float*)d_in[11];
    const float* g_up1 = (const float*)d_in[12]; const float* b_up1 = (const float*)d_in[13];
    const float* g_up0 = (const float*)d_in[14]; const float* b_up0 = (const float*)d_in[15];
    const float* g_s0  = (const float*)d_in[16]; const float* b_s0  = (const float*)d_in[17];
    const float* g_s1  = (const float*)d_in[18]; const float* b_s1  = (const float*)d_in[19];
    const float* g_s2  = (const float*)d_in[20]; const float* b_s2  = (const float*)d_in[21];
    const int* up2_in  = (const int*)d_in[22]; const int* up2_out = (const int*)d_in[23];
    const int* up1_in  = (const int*)d_in[24]; const int* up1_out = (const int*)d_in[25];
    const int* up0_in  = (const int*)d_in[26]; const int* up0_out = (const int*)d_in[27];
    const int* sm0_in  = (const int*)d_in[28]; const int* sm0_out = (const int*)d_in[29];
    const int* sm1_in  = (const int*)d_in[30]; const int* sm1_out = (const int*)d_in[31];

    char* ws = (char*)d_ws;
    auto alloc = [&](size_t bytes) { char* p = ws; ws += (bytes + 255) & ~(size_t)255; return p; };

    unsigned short* WT_up2 = (unsigned short*)alloc((size_t)27 * 128 * 128 * 2);
    unsigned short* WT_up1 = (unsigned short*)alloc((size_t)27 * 192 * 192 * 2);
    unsigned short* WT_up0 = (unsigned short*)alloc((size_t)27 * 224 * 224 * 2);
    unsigned short* WT_s0  = (unsigned short*)alloc((size_t)27 * 512 * 256 * 2);
    unsigned short* WT_s1  = (unsigned short*)alloc((size_t)27 * 512 * 512 * 2);
    unsigned short* WT_s2  = (unsigned short*)alloc((size_t)512 * 512 * 2);
    unsigned short* xb3 = (unsigned short*)alloc((size_t)2000 * 128 * 2);
    unsigned short* xc2 = (unsigned short*)alloc((size_t)5000 * 192 * 2);
    unsigned short* xc1 = (unsigned short*)alloc((size_t)12000 * 224 * 2);
    unsigned short* xc0 = (unsigned short*)alloc((size_t)30000 * 256 * 2);
    unsigned short* ys0 = (unsigned short*)alloc((size_t)30000 * 512 * 2);
    unsigned short* ys1 = (unsigned short*)alloc((size_t)30000 * 512 * 2);
    float* acc   = (float*)alloc((size_t)30000 * 512 * 4);   // reused by all conv layers
    float* stats = (float*)alloc((size_t)6 * 1024 * 4);
    float* out_f = (float*)d_out;

    // ---- weight prep (bf16, transposed to [k][cout][cin]) ----
    transpose_cast_w<<<dim3(4, 4, 27),  256, 0, stream>>>(W_up2, WT_up2, 128, 128, 128);
    transpose_cast_w<<<dim3(6, 6, 27),  256, 0, stream>>>(W_up1, WT_up1, 192, 192, 192);
    transpose_cast_w<<<dim3(7, 7, 27),  256, 0, stream>>>(W_up0, WT_up0, 224, 224, 224);
    transpose_cast_w<<<dim3(16, 8, 27), 256, 0, stream>>>(W_s0,  WT_s0,  240, 512, 256);
    transpose_cast_w<<<dim3(16, 16, 27),256, 0, stream>>>(W_s1,  WT_s1,  512, 512, 512);
    transpose_cast_w<<<dim3(16, 16, 1), 256, 0, stream>>>(W_s2,  WT_s2,  512, 512, 512);
    cast_cols<<<div_up(2000 * 128, 256), 256, 0, stream>>>(f3, xb3, 2000, 128, 128, 0, 128);
    hipMemsetAsync(stats, 0, (size_t)6 * 1024 * 4, stream);

    // ---- up2: [2000,128] -> conv -> [5000,128], concat f2 -> xc2 [5000,192] ----
    hipMemsetAsync(acc, 0, (size_t)5000 * 128 * 4, stream);
    conv_mfma<64, 64, false><<<dim3(25, 2, 27), 256, 0, stream>>>(xb3, WT_up2, up2_in, up2_out, acc, 1600, 128, 128);
    bn_stats<<<div_up(5000, 64), 256, 0, stream>>>(acc, stats + 0 * 1024, 5000, 128, 64);
    bn_apply_bf16<<<div_up(5000 * 128, 256), 256, 0, stream>>>(acc, stats + 0 * 1024, g_up2, b_up2, xc2, 5000, 128, 192, 1.f / 5000);
    cast_cols<<<div_up(5000 * 64, 256), 256, 0, stream>>>(f2, xc2, 5000, 64, 192, 128, 64);

    // ---- up1: [5000,192] -> conv -> [12000,192], concat f1 -> xc1 [12000,224] ----
    hipMemsetAsync(acc, 0, (size_t)12000 * 192 * 4, stream);
    conv_mfma<64, 64, false><<<dim3(63, 3, 27), 256, 0, stream>>>(xc2, WT_up1, up1_in, up1_out, acc, 4000, 192, 192);
    bn_stats<<<div_up(12000, 64), 256, 0, stream>>>(acc, stats + 1 * 1024, 12000, 192, 64);
    bn_apply_bf16<<<div_up(12000 * 192, 256), 256, 0, stream>>>(acc, stats + 1 * 1024, g_up1, b_up1, xc1, 12000, 192, 224, 1.f / 12000);
    cast_cols<<<div_up(12000 * 32, 256), 256, 0, stream>>>(f1, xc1, 12000, 32, 224, 192, 32);

    // ---- up0: [12000,224] -> conv -> [30000,224], concat f0+pad -> xc0 [30000,256] ----
    hipMemsetAsync(acc, 0, (size_t)30000 * 224 * 4, stream);
    conv_mfma<64, 32, false><<<dim3(157, 7, 27), 256, 0, stream>>>(xc1, WT_up0, up0_in, up0_out, acc, 10000, 224, 224);
    bn_stats<<<div_up(30000, 64), 256, 0, stream>>>(acc, stats + 2 * 1024, 30000, 224, 64);
    bn_apply_bf16<<<div_up(30000 * 224, 256), 256, 0, stream>>>(acc, stats + 2 * 1024, g_up0, b_up0, xc0, 30000, 224, 256, 1.f / 30000);
    cast_cols<<<div_up(30000 * 32, 256), 256, 0, stream>>>(f0, xc0, 30000, 16, 256, 224, 32); // 16 real + 16 zero pad

    // ---- s0: [30000,256pad] -> conv -> [30000,512] -> ys0 ----
    hipMemsetAsync(acc, 0, (size_t)30000 * 512 * 4, stream);
    conv_mfma<64, 64, false><<<dim3(157, 8, 27), 256, 0, stream>>>(xc0, WT_s0, sm0_in, sm0_out, acc, 10000, 256, 512);
    bn_stats<<<div_up(30000, 64), 256, 0, stream>>>(acc, stats + 3 * 1024, 30000, 512, 64);
    bn_apply_bf16<<<div_up(30000 * 512, 256), 256, 0, stream>>>(acc, stats + 3 * 1024, g_s0, b_s0, ys0, 30000, 512, 512, 1.f / 30000);

    // ---- s1: [30000,512] -> conv -> [30000,512] -> ys1 ----
    hipMemsetAsync(acc, 0, (size_t)30000 * 512 * 4, stream);
    conv_mfma<64, 64, false><<<dim3(157, 8, 27), 256, 0, stream>>>(ys0, WT_s1, sm1_in, sm1_out, acc, 10000, 512, 512);
    bn_stats<<<div_up(30000, 64), 256, 0, stream>>>(acc, stats + 4 * 1024, 30000, 512, 64);
    bn_apply_bf16<<<div_up(30000 * 512, 256), 256, 0, stream>>>(acc, stats + 4 * 1024, g_s1, b_s1, ys1, 30000, 512, 512, 1.f / 30000);

    // ---- s2: dense [30000,512] @ [512,512] -> d_out, BN+ReLU in place ----
    conv_mfma<64, 64, true><<<dim3(469, 8, 1), 256, 0, stream>>>(ys1, WT_s2, nullptr, nullptr, out_f, 30000, 512, 512);
    bn_stats<<<div_up(30000, 64), 256, 0, stream>>>(out_f, stats + 5 * 1024, 30000, 512, 64);
    bn_apply_f32<<<div_up(30000 * 512, 256), 256, 0, stream>>>(out_f, stats + 5 * 1024, g_s2, b_s2, 30000, 512, 1.f / 30000);
}

// Round 3
// 1834.658 us; speedup vs baseline: 1.0828x; 1.0828x over previous
//
#include <hip/hip_runtime.h>

typedef short bf16x8 __attribute__((ext_vector_type(8)));
typedef float f32x4 __attribute__((ext_vector_type(4)));

#define BN_EPS 1e-5f
#define ELL_CAP 64

__device__ __forceinline__ unsigned short f2b(float x) {
    union { float f; unsigned u; } v; v.f = x;
    unsigned r = v.u + 0x7FFFu + ((v.u >> 16) & 1u);
    return (unsigned short)(r >> 16);
}
__device__ __forceinline__ float b2f(unsigned short h) {
    union { unsigned u; float f; } v; v.u = ((unsigned)h) << 16;
    return v.f;
}
__device__ __forceinline__ void atomAddF(float* p, float v) { unsafeAtomicAdd(p, v); }

__device__ __forceinline__ void gload16(const void* g, void* l) {
    __builtin_amdgcn_global_load_lds((const __attribute__((address_space(1))) void*)g,
                                     (__attribute__((address_space(3))) void*)l, 16, 0, 0);
}

// ---- W[k][ci][co] f32 -> WT[k][coPad][ciPad] bf16 (zero-padded both dims) ----
__global__ void transpose_cast_w(const float* __restrict__ W, unsigned short* __restrict__ WT,
                                 int Cin, int Cout, int CinPad, int CoutPad) {
    __shared__ float t[32][33];
    int co0 = blockIdx.x * 32, ci0 = blockIdx.y * 32, k = blockIdx.z;
    const float* Wk = W + (size_t)k * Cin * Cout;
    unsigned short* WTk = WT + (size_t)k * CoutPad * CinPad;
    int tc = threadIdx.x & 31, tr = threadIdx.x >> 5;
    for (int i = 0; i < 4; i++) {
        int r = tr + i * 8;
        int ci = ci0 + r, co = co0 + tc;
        t[r][tc] = (ci < Cin && co < Cout) ? Wk[(size_t)ci * Cout + co] : 0.f;
    }
    __syncthreads();
    for (int i = 0; i < 4; i++) {
        int r = tr + i * 8;
        WTk[(size_t)(co0 + r) * CinPad + ci0 + tc] = f2b(t[tc][r]);
    }
}

// ---- cast fp32 [N,Csrc] -> bf16 dst[n*stride + off + j], zero-fill j>=Csrc ----
__global__ void cast_cols(const float* __restrict__ src, unsigned short* __restrict__ dst,
                          int N, int Csrc, int stride, int off, int wid) {
    int i = blockIdx.x * blockDim.x + threadIdx.x;
    if (i >= N * wid) return;
    int n = i / wid, j = i % wid;
    float v = (j < Csrc) ? src[(size_t)n * Csrc + j] : 0.f;
    dst[(size_t)n * stride + off + j] = f2b(v);
}

// ---- BN stats: per-channel sum & sumsq ----
__global__ void bn_stats(const float* __restrict__ x, float* __restrict__ stats,
                         int N, int C, int rowsPerBlock) {
    int r0 = blockIdx.x * rowsPerBlock;
    int r1 = min(N, r0 + rowsPerBlock);
    for (int c = threadIdx.x; c < C; c += blockDim.x) {
        float s = 0.f, s2 = 0.f;
        for (int r = r0; r < r1; r++) {
            float v = x[(size_t)r * C + c];
            s += v; s2 += v * v;
        }
        atomAddF(&stats[c], s);
        atomAddF(&stats[C + c], s2);
    }
}

// ---- BN apply + ReLU -> bf16 (strided dst, for concat) ----
__global__ void bn_apply_bf16(const float* __restrict__ x, const float* __restrict__ stats,
                              const float* __restrict__ g, const float* __restrict__ b,
                              unsigned short* __restrict__ dst, int N, int C, int stride, float invN) {
    int i = blockIdx.x * blockDim.x + threadIdx.x;
    if (i >= N * C) return;
    int n = i / C, c = i % C;
    float mean = stats[c] * invN;
    float var = stats[C + c] * invN - mean * mean;
    float scale = g[c] * rsqrtf(var + BN_EPS);
    float shift = b[c] - mean * scale;
    float y = fmaxf(0.f, x[i] * scale + shift);
    dst[(size_t)n * stride + c] = f2b(y);
}

// ---- BN apply + ReLU in-place fp32 (final output) ----
__global__ void bn_apply_f32(float* __restrict__ x, const float* __restrict__ stats,
                             const float* __restrict__ g, const float* __restrict__ b,
                             int N, int C, float invN) {
    int i = blockIdx.x * blockDim.x + threadIdx.x;
    if (i >= N * C) return;
    int c = i % C;
    float mean = stats[c] * invN;
    float var = stats[C + c] * invN - mean * mean;
    float scale = g[c] * rsqrtf(var + BN_EPS);
    float shift = b[c] - mean * scale;
    x[i] = fmaxf(0.f, x[i] * scale + shift);
}

// ---- inverse-index (ELL) build: entry e = k*M+m ----
__global__ void ell_build(const int* __restrict__ out_idx, int total,
                          int* __restrict__ cnt, int* __restrict__ ell) {
    int e = blockIdx.x * blockDim.x + threadIdx.x;
    if (e >= total) return;
    int o = out_idx[e];
    int pos = atomicAdd(&cnt[o], 1);
    if (pos < ELL_CAP) ell[(size_t)o * ELL_CAP + pos] = e;
}

// ---- Phase B: per-output-row gather of bf16 partials in k-range, sum fp32 ----
__global__ __launch_bounds__(256)
void reduce_ell(const unsigned short* __restrict__ c, const int* __restrict__ cnt,
                const int* __restrict__ ell, float* __restrict__ out,
                int Np, int Cout, int Nout, int k0row, int k1row, int accum) {
    int wave = threadIdx.x >> 6, lane = threadIdx.x & 63;
    int col = lane * 8;
    for (int rr = 0; rr < 8; rr++) {
        int o = blockIdx.x * 32 + wave * 8 + rr;
        if (o >= Nout) break;
        int n = min(cnt[o], ELL_CAP);
        float a[8];
        #pragma unroll
        for (int j = 0; j < 8; j++) a[j] = 0.f;
        if (col < Np) {
            const int* ellrow = ell + (size_t)o * ELL_CAP;
            for (int i = 0; i < n; i++) {
                int krow = ellrow[i];
                if (krow < k0row || krow >= k1row) continue;
                bf16x8 v = *(const bf16x8*)(c + (size_t)(krow - k0row) * Np + col);
                #pragma unroll
                for (int j = 0; j < 8; j++) a[j] += b2f((unsigned short)v[j]);
            }
        }
        if (col < Cout) {
            float* op = out + (size_t)o * Cout + col;
            if (accum) {
                float4 lo = *(const float4*)op;
                float4 hi = *(const float4*)(op + 4);
                a[0] += lo.x; a[1] += lo.y; a[2] += lo.z; a[3] += lo.w;
                a[4] += hi.x; a[5] += hi.y; a[6] += hi.z; a[7] += hi.w;
            }
            float4 lo = {a[0], a[1], a[2], a[3]}, hi = {a[4], a[5], a[6], a[7]};
            *(float4*)op = lo;
            *(float4*)(op + 4) = hi;
        }
    }
}

// ---- Phase A: per-k dense GEMM, 128x128 tile, BK=32, global_load_lds staging ----
// kz_global = kbase + blockIdx.z; partials written chunk-local at blockIdx.z
template<bool DENSE>
__global__ __launch_bounds__(256)
void spconv_gemm(const unsigned short* __restrict__ A, const unsigned short* __restrict__ BT,
                 const int* __restrict__ in_idx, unsigned short* __restrict__ cpart,
                 float* __restrict__ outf, int M, int Kp, int Np, int kbase) {
    // seg-major 16B chunks: chunk(seg,row) = seg*128+row. global_load_lds lane-ordered
    // AND 2-way-max bank aliasing on ds_read_b128.
    __shared__ __align__(16) unsigned short As[128 * 32];
    __shared__ __align__(16) unsigned short Bs[128 * 32];
    int tid = threadIdx.x, wave = tid >> 6, lane = tid & 63;
    int wr = wave >> 1, wc = wave & 1;
    int m0 = blockIdx.x * 128, n0 = blockIdx.y * 128;
    int kzl = blockIdx.z, kz = kbase + kzl;

    int r0 = m0 + lane, r1 = r0 + 64;
    size_t arow0, arow1;
    if constexpr (DENSE) {
        arow0 = (size_t)min(r0, M - 1);
        arow1 = (size_t)min(r1, M - 1);
    } else {
        const int* idxk = in_idx + (size_t)kz * M;
        arow0 = (r0 < M) ? (size_t)idxk[r0] : 0;
        arow1 = (r1 < M) ? (size_t)idxk[r1] : 0;
    }
    const unsigned short* gA0 = A + arow0 * Kp + wave * 8;
    const unsigned short* gA1 = A + arow1 * Kp + wave * 8;
    const unsigned short* BTk = BT + (size_t)kz * Np * Kp;
    const unsigned short* gB0 = BTk + (size_t)(n0 + lane) * Kp + wave * 8;
    const unsigned short* gB1 = BTk + (size_t)(n0 + 64 + lane) * Kp + wave * 8;
    unsigned short* lA0 = As + (wave * 128) * 8;
    unsigned short* lA1 = As + (wave * 128 + 64) * 8;
    unsigned short* lB0 = Bs + (wave * 128) * 8;
    unsigned short* lB1 = Bs + (wave * 128 + 64) * 8;

    f32x4 acc[4][4];
    #pragma unroll
    for (int i = 0; i < 4; i++)
        #pragma unroll
        for (int j = 0; j < 4; j++) acc[i][j] = (f32x4)(0.f);

    int laneM = lane & 15, seg = lane >> 4;
    const unsigned short* afp = As + (size_t)(seg * 128 + wr * 64 + laneM) * 8;
    const unsigned short* bfp = Bs + (size_t)(seg * 128 + wc * 64 + laneM) * 8;

    for (int kc = 0; kc < Kp; kc += 32) {
        __syncthreads();
        gload16(gA0 + kc, lA0);
        gload16(gA1 + kc, lA1);
        gload16(gB0 + kc, lB0);
        gload16(gB1 + kc, lB1);
        __syncthreads();
        bf16x8 af[4], bfr[4];
        #pragma unroll
        for (int i = 0; i < 4; i++) af[i] = *(const bf16x8*)(afp + i * 16 * 8);
        #pragma unroll
        for (int j = 0; j < 4; j++) bfr[j] = *(const bf16x8*)(bfp + j * 16 * 8);
        #pragma unroll
        for (int i = 0; i < 4; i++)
            #pragma unroll
            for (int j = 0; j < 4; j++)
                acc[i][j] = __builtin_amdgcn_mfma_f32_16x16x32_bf16(af[i], bfr[j], acc[i][j], 0, 0, 0);
    }

    // C/D layout: col=lane&15, row=(lane>>4)*4+r  [m89/m91 verified]
    int rbase = seg * 4;
    #pragma unroll
    for (int i = 0; i < 4; i++) {
        #pragma unroll
        for (int r = 0; r < 4; r++) {
            int gm = m0 + wr * 64 + i * 16 + rbase + r;
            if (gm < M) {
                #pragma unroll
                for (int j = 0; j < 4; j++) {
                    int col = n0 + wc * 64 + j * 16 + laneM;
                    if constexpr (DENSE) {
                        outf[(size_t)gm * Np + col] = acc[i][j][r];
                    } else {
                        cpart[((size_t)kzl * M + gm) * Np + col] = f2b(acc[i][j][r]);
                    }
                }
            }
        }
    }
}

static inline int div_up(int a, int b) { return (a + b - 1) / b; }

extern "C" void kernel_launch(void* const* d_in, const int* in_sizes, int n_in,
                              void* d_out, int out_size, void* d_ws, size_t ws_size,
                              hipStream_t stream) {
    const float* f0 = (const float*)d_in[0];
    const float* f1 = (const float*)d_in[1];
    const float* f2 = (const float*)d_in[2];
    const float* f3 = (const float*)d_in[3];
    const float* W_up2 = (const float*)d_in[4];
    const float* W_up1 = (const float*)d_in[5];
    const float* W_up0 = (const float*)d_in[6];
    const float* W_s0  = (const float*)d_in[7];
    const float* W_s1  = (const float*)d_in[8];
    const float* W_s2  = (const float*)d_in[9];
    const float* g_up2 = (const float*)d_in[10]; const float* b_up2 = (const float*)d_in[11];
    const float* g_up1 = (const float*)d_in[12]; const float* b_up1 = (const float*)d_in[13];
    const float* g_up0 = (const float*)d_in[14]; const float* b_up0 = (const float*)d_in[15];
    const float* g_s0  = (const float*)d_in[16]; const float* b_s0  = (const float*)d_in[17];
    const float* g_s1  = (const float*)d_in[18]; const float* b_s1  = (const float*)d_in[19];
    const float* g_s2  = (const float*)d_in[20]; const float* b_s2  = (const float*)d_in[21];
    const int* up2_in  = (const int*)d_in[22]; const int* up2_out = (const int*)d_in[23];
    const int* up1_in  = (const int*)d_in[24]; const int* up1_out = (const int*)d_in[25];
    const int* up0_in  = (const int*)d_in[26]; const int* up0_out = (const int*)d_in[27];
    const int* sm0_in  = (const int*)d_in[28]; const int* sm0_out = (const int*)d_in[29];
    const int* sm1_in  = (const int*)d_in[30]; const int* sm1_out = (const int*)d_in[31];

    char* ws = (char*)d_ws;
    auto alloc = [&](size_t bytes) { char* p = ws; ws += (bytes + 255) & ~(size_t)255; return p; };

    // weights bf16 WT[k][CoutPad][CinPad]
    unsigned short* WT_up2 = (unsigned short*)alloc((size_t)27 * 128 * 128 * 2);
    unsigned short* WT_up1 = (unsigned short*)alloc((size_t)27 * 256 * 192 * 2);
    unsigned short* WT_up0 = (unsigned short*)alloc((size_t)27 * 256 * 224 * 2);
    unsigned short* WT_s0  = (unsigned short*)alloc((size_t)27 * 512 * 256 * 2);
    unsigned short* WT_s1  = (unsigned short*)alloc((size_t)27 * 512 * 512 * 2);
    unsigned short* WT_s2  = (unsigned short*)alloc((size_t)512 * 512 * 2);
    // activations bf16
    unsigned short* xb3 = (unsigned short*)alloc((size_t)2000 * 128 * 2);
    unsigned short* xc2 = (unsigned short*)alloc((size_t)5000 * 192 * 2);
    unsigned short* xc1 = (unsigned short*)alloc((size_t)12000 * 224 * 2);
    unsigned short* xc0 = (unsigned short*)alloc((size_t)30000 * 256 * 2);
    unsigned short* ys  = (unsigned short*)alloc((size_t)30000 * 512 * 2);  // s0 out, then s1 out
    float* outb = (float*)alloc((size_t)30000 * 512 * 4);
    int* cnt = (int*)alloc((size_t)30000 * 4);
    int* ell = (int*)alloc((size_t)30000 * ELL_CAP * 4);
    float* stats = (float*)alloc((size_t)6 * 1024 * 4);
    // c partials: everything that's left
    size_t used = (size_t)(ws - (char*)d_ws);
    size_t cBudget = (ws_size > used + (1u << 20)) ? (ws_size - used - (1u << 20)) : 0;
    unsigned short* c = (unsigned short*)ws;

    // ---- prep ----
    transpose_cast_w<<<dim3(4, 4, 27),  256, 0, stream>>>(W_up2, WT_up2, 128, 128, 128, 128);
    transpose_cast_w<<<dim3(8, 6, 27),  256, 0, stream>>>(W_up1, WT_up1, 192, 192, 192, 256);
    transpose_cast_w<<<dim3(8, 7, 27),  256, 0, stream>>>(W_up0, WT_up0, 224, 224, 224, 256);
    transpose_cast_w<<<dim3(16, 8, 27), 256, 0, stream>>>(W_s0,  WT_s0,  240, 512, 256, 512);
    transpose_cast_w<<<dim3(16, 16, 27),256, 0, stream>>>(W_s1,  WT_s1,  512, 512, 512, 512);
    transpose_cast_w<<<dim3(16, 16, 1), 256, 0, stream>>>(W_s2,  WT_s2,  512, 512, 512, 512);
    cast_cols<<<div_up(2000 * 128, 256), 256, 0, stream>>>(f3, xb3, 2000, 128, 128, 0, 128);
    hipMemsetAsync(stats, 0, (size_t)6 * 1024 * 4, stream);

    // sparse conv layer driver: chunked over k per available c budget
    auto conv_layer = [&](const unsigned short* Ain, const unsigned short* WT,
                          const int* in_idx, const int* out_idx,
                          int M, int Kp, int Np, int Cout, int Nout) {
        hipMemsetAsync(cnt, 0, (size_t)Nout * 4, stream);
        ell_build<<<div_up(27 * M, 256), 256, 0, stream>>>(out_idx, 27 * M, cnt, ell);
        size_t bytesPerK = (size_t)M * Np * 2;
        int CK = (int)(cBudget / bytesPerK);
        if (CK < 1) CK = 1;
        if (CK > 27) CK = 27;
        for (int k0 = 0; k0 < 27; k0 += CK) {
            int ck = (27 - k0 < CK) ? (27 - k0) : CK;
            spconv_gemm<false><<<dim3(div_up(M, 128), Np / 128, ck), 256, 0, stream>>>(
                Ain, WT, in_idx, c, nullptr, M, Kp, Np, k0);
            reduce_ell<<<div_up(Nout, 32), 256, 0, stream>>>(
                c, cnt, ell, outb, Np, Cout, Nout, k0 * M, (k0 + ck) * M, k0 > 0 ? 1 : 0);
        }
    };

    // ---- up2: xb3[2000,128] -> [5000,128]; concat f2 -> xc2[5000,192] ----
    conv_layer(xb3, WT_up2, up2_in, up2_out, 1600, 128, 128, 128, 5000);
    bn_stats<<<div_up(5000, 64), 256, 0, stream>>>(outb, stats + 0 * 1024, 5000, 128, 64);
    bn_apply_bf16<<<div_up(5000 * 128, 256), 256, 0, stream>>>(outb, stats + 0 * 1024, g_up2, b_up2, xc2, 5000, 128, 192, 1.f / 5000);
    cast_cols<<<div_up(5000 * 64, 256), 256, 0, stream>>>(f2, xc2, 5000, 64, 192, 128, 64);

    // ---- up1: xc2[5000,192] -> [12000,192]; concat f1 -> xc1[12000,224] ----
    conv_layer(xc2, WT_up1, up1_in, up1_out, 4000, 192, 256, 192, 12000);
    bn_stats<<<div_up(12000, 64), 256, 0, stream>>>(outb, stats + 1 * 1024, 12000, 192, 64);
    bn_apply_bf16<<<div_up(12000 * 192, 256), 256, 0, stream>>>(outb, stats + 1 * 1024, g_up1, b_up1, xc1, 12000, 192, 224, 1.f / 12000);
    cast_cols<<<div_up(12000 * 32, 256), 256, 0, stream>>>(f1, xc1, 12000, 32, 224, 192, 32);

    // ---- up0: xc1[12000,224] -> [30000,224]; concat f0+pad -> xc0[30000,256] ----
    conv_layer(xc1, WT_up0, up0_in, up0_out, 10000, 224, 256, 224, 30000);
    bn_stats<<<div_up(30000, 64), 256, 0, stream>>>(outb, stats + 2 * 1024, 30000, 224, 64);
    bn_apply_bf16<<<div_up(30000 * 224, 256), 256, 0, stream>>>(outb, stats + 2 * 1024, g_up0, b_up0, xc0, 30000, 224, 256, 1.f / 30000);
    cast_cols<<<div_up(30000 * 32, 256), 256, 0, stream>>>(f0, xc0, 30000, 16, 256, 224, 32); // 16 real + 16 pad

    // ---- s0: xc0[30000,256] -> [30000,512] -> ys ----
    conv_layer(xc0, WT_s0, sm0_in, sm0_out, 10000, 256, 512, 512, 30000);
    bn_stats<<<div_up(30000, 64), 256, 0, stream>>>(outb, stats + 3 * 1024, 30000, 512, 64);
    bn_apply_bf16<<<div_up(30000 * 512, 256), 256, 0, stream>>>(outb, stats + 3 * 1024, g_s0, b_s0, ys, 30000, 512, 512, 1.f / 30000);

    // ---- s1: ys[30000,512] -> [30000,512] -> ys (overwritten after reduce) ----
    conv_layer(ys, WT_s1, sm1_in, sm1_out, 10000, 512, 512, 512, 30000);
    bn_stats<<<div_up(30000, 64), 256, 0, stream>>>(outb, stats + 4 * 1024, 30000, 512, 64);
    bn_apply_bf16<<<div_up(30000 * 512, 256), 256, 0, stream>>>(outb, stats + 4 * 1024, g_s1, b_s1, ys, 30000, 512, 512, 1.f / 30000);

    // ---- s2: dense ys[30000,512] @ W -> d_out, BN+ReLU in place ----
    float* out_f = (float*)d_out;
    spconv_gemm<true><<<dim3(235, 4, 1), 256, 0, stream>>>(ys, WT_s2, nullptr, nullptr, out_f, 30000, 512, 512, 0);
    bn_stats<<<div_up(30000, 64), 256, 0, stream>>>(out_f, stats + 5 * 1024, 30000, 512, 64);
    bn_apply_f32<<<div_up(30000 * 512, 256), 256, 0, stream>>>(out_f, stats + 5 * 1024, g_s2, b_s2, 30000, 512, 1.f / 30000);
}